// Round 7
// baseline (78.707 us; speedup 1.0000x reference)
//
#include <hip/hip_runtime.h>

// PartChamferLoss: src/dst [B=16, K=8, 3, 1024] f32 -> scalar f32.
// R7: force v_pk_fma_f32 (packed fp32, 2 FMA/inst) via inline asm.
// Targets pair-packed in LDS: [2p]={x0,x1,y0,y1}, [2p+1]={z0,z1,w0,w1},
// so every pk_fma operand is a natural VGPR pair (zero per-step movs).
// Inner cost per target: 12 pk_fma + 8 v_min + 1 ds_read_b128.
// Structure otherwise identical to R6 (8 target-splits, LDS atomicMin
// combine, plain part[] store + tiny finisher, no memset).

typedef float v2f __attribute__((ext_vector_type(2)));

#define NPTS 1024
#define TPB 1024
#define NSPLIT 8
#define QPT 8
#define TGT (NPTS / NSPLIT)        // 128 targets per split
#define PAIRS (TGT / 2)            // 64 target-pairs per split

__device__ __forceinline__ v2f pk_fma(v2f a, v2f b, v2f c) {
  v2f d;
  asm("v_pk_fma_f32 %0, %1, %2, %3" : "=v"(d) : "v"(a), "v"(b), "v"(c));
  return d;
}

__global__ __launch_bounds__(TPB) void chamfer_main_kernel(
    const float* __restrict__ src,  // [BK, 3, NPTS]
    const float* __restrict__ dst,  // [BK, 3, NPTS]
    float* __restrict__ part,       // [2*BK] block partials
    int BK) {
  // pair-packed targets: 512 pairs x 32B = 16 KB
  __shared__ float4 tgt[NPTS];
  __shared__ unsigned cmb[NPTS];   // [j][qg] combine buffer
  __shared__ float wsum[2];

  const int t = threadIdx.x;
  const int pair = blockIdx.x;          // dir*BK + bk
  const int dir = pair >= BK;
  const int bk = dir ? (pair - BK) : pair;
  const float* A = (dir ? dst : src) + (size_t)bk * 3 * NPTS;   // queries
  const float* Bb = (dir ? src : dst) + (size_t)bk * 3 * NPTS;  // targets

  // Init combine buffer; stage 512 target-pairs (threads 0-511).
  cmb[t] = 0x7F800000u;  // +inf
  if (t < NPTS / 2) {
    const int p = t;
    float x0 = Bb[2 * p],            x1 = Bb[2 * p + 1];
    float y0 = Bb[NPTS + 2 * p],     y1 = Bb[NPTS + 2 * p + 1];
    float z0 = Bb[2 * NPTS + 2 * p], z1 = Bb[2 * NPTS + 2 * p + 1];
    float w0 = fmaf(x0, x0, fmaf(y0, y0, z0 * z0));
    float w1 = fmaf(x1, x1, fmaf(y1, y1, z1 * z1));
    tgt[2 * p]     = make_float4(x0, x1, y0, y1);
    tgt[2 * p + 1] = make_float4(z0, z1, w0, w1);
  }
  __syncthreads();

  const int qg = t & 127;    // query group: queries qg + j*128
  const int split = t >> 7;  // wave-uniform (64 | 128)

  // 8 queries/thread; coefficients pre-broadcast into v2f pairs (prologue
  // movs amortized over the whole loop).
  v2f axp[QPT], ayp[QPT], azp[QPT], mnp[QPT];
  float sq[QPT];
#pragma unroll
  for (int j = 0; j < QPT; ++j) {
    const int m = qg + j * 128;
    float x = A[m], y = A[NPTS + m], z = A[2 * NPTS + m];
    float ax = -2.0f * x, ay = -2.0f * y, az = -2.0f * z;
    axp[j] = (v2f){ax, ax};
    ayp[j] = (v2f){ay, ay};
    azp[j] = (v2f){az, az};
    sq[j] = fmaf(x, x, fmaf(y, y, z * z));
    mnp[j] = (v2f){3.4e38f, 3.4e38f};
  }

  // Inner loop: 64 pair-steps over this split's 128 targets.
  const float4* ts = &tgt[split * 2 * PAIRS];
#pragma unroll 4
  for (int p = 0; p < PAIRS; ++p) {
    float4 lo = ts[2 * p];      // {x0, x1, y0, y1}  (wave-uniform broadcast)
    float4 hi = ts[2 * p + 1];  // {z0, z1, w0, w1}
    v2f xx = {lo.x, lo.y}, yy = {lo.z, lo.w};
    v2f zz = {hi.x, hi.y}, ww = {hi.z, hi.w};
#pragma unroll
    for (int j = 0; j < QPT; ++j) {
      v2f v = pk_fma(azp[j], zz, ww);   // sq_n - 2*dot, two targets at once
      v = pk_fma(ayp[j], yy, v);
      v = pk_fma(axp[j], xx, v);
      mnp[j].x = fminf(mnp[j].x, v.x);  // no pk_min on CDNA -> scalar mins
      mnp[j].y = fminf(mnp[j].y, v.y);
    }
  }

  // Fold target-pair halves, add sq_q, clamp, combine across 8 splits.
#pragma unroll
  for (int j = 0; j < QPT; ++j) {
    float m = sq[j] + fminf(mnp[j].x, mnp[j].y);
    m = fmaxf(m, 0.0f);
    atomicMin(&cmb[j * 128 + qg], __float_as_uint(m));
  }
  __syncthreads();

  // Waves 0-1: sqrt + sum the 1024 final mins; one plain store per block.
  if (t < 128) {
    float v = 0.0f;
#pragma unroll
    for (int j = 0; j < QPT; ++j)
      v += sqrtf(__uint_as_float(cmb[j * 128 + t]));
    for (int off = 32; off > 0; off >>= 1) v += __shfl_down(v, off);
    if ((t & 63) == 0) wsum[t >> 6] = v;
  }
  __syncthreads();
  if (t == 0) part[pair] = wsum[0] + wsum[1];
}

__global__ __launch_bounds__(256) void chamfer_final_kernel(
    const float* __restrict__ part, float* __restrict__ out, int n,
    float scale) {
  const int t = threadIdx.x;
  float v = (t < n) ? part[t] : 0.0f;
  for (int off = 32; off > 0; off >>= 1) v += __shfl_down(v, off);
  __shared__ float wsum[4];
  if ((t & 63) == 0) wsum[t >> 6] = v;
  __syncthreads();
  if (t == 0) out[0] = (wsum[0] + wsum[1] + wsum[2] + wsum[3]) * scale;
}

extern "C" void kernel_launch(void* const* d_in, const int* in_sizes, int n_in,
                              void* d_out, int out_size, void* d_ws, size_t ws_size,
                              hipStream_t stream) {
  const float* src = (const float*)d_in[0];  // [B,K,3,M]
  const float* dst = (const float*)d_in[1];  // [B,K,3,N]
  float* out = (float*)d_out;                // scalar f32
  float* partbuf = (float*)d_ws;             // 256 floats of scratch

  const int BK = in_sizes[0] / (3 * NPTS);        // 16*8 = 128
  const float scale = 1.0f / (float)(BK * NPTS);  // 1/(B*K*M), M==N

  dim3 grid(2 * BK);  // 256 blocks of 1024 threads
  chamfer_main_kernel<<<grid, TPB, 0, stream>>>(src, dst, partbuf, BK);
  chamfer_final_kernel<<<1, 256, 0, stream>>>(partbuf, out, 2 * BK, scale);
}